// Round 9
// baseline (118.127 us; speedup 1.0000x reference)
//
#include <hip/hip_runtime.h>
#include <math.h>

#define TWO_PI_F 6.28318530717958647692f
#define BN_EPS_F 1e-5f

// barrier-kernel config: 1024 blocks * 256 thr = 4 blocks/CU on 256 CUs
#define NBLK 1024
#define NT 256
#define NLEAF 32   // barrier tree: 32 leaves x 32 blocks
#define MKSH 16    // min/max shards (write side)
#define STSH 8     // BN stat shards (write depth 128/line; read 64 loads/blk)

// fallback (proven 3-kernel) config
#define NB1 2048
#define NB2 1024

// ---------------------------------------------------------------------------
// Workspace layout (uint offsets on u = (unsigned*)wsf; contended slots on
// their own cachelines). Cross-block data via RELAXED device-scope atomics.
// KEY LESSON (R8): agent-scope atomic LOADS are RMW-class at the coherence
// point (~64B fetch + ~128B writeback EACH) -- keep their COUNT tiny.
// Consumer reads are single-wave-per-block only.
//   MK     : u[s*32] min key, u[s*32+16] max key, s<16            [0..512)
//   LEAFA  : u[512  + l*32]  sync-A leaf counters                  [512..1536)
//   FLAGA  : u[1536 + l*32]  sync-A per-leaf release flags         [1536..2560)
//   ROOTA  : u[2560]                                               [2560..2592)
//   LEAFB  : u[2592 + l*32]                                        [2592..3616)
//   FLAGB  : u[3616 + l*32]                                        [3616..4640)
//   ROOTB  : u[4640]                                               [4640..4672)
// float offsets on wsf:
//   STAT   : wsf[4672 + s*16 + j], s<8, j<8 (atomicAdd shards)     [4672..4800)
//   CTAB   : UrT[256] | UiT[256] | AT[64]                          [5696..6272)
// Fallback keeps its proven layout (paths mutually exclusive).
// ---------------------------------------------------------------------------
#define MK_OFF 0
#define LEAFA_OFF 512
#define FLAGA_OFF 1536
#define ROOTA_OFF 2560
#define LEAFB_OFF 2592
#define FLAGB_OFF 3616
#define ROOTB_OFF 4640
#define UZERO_N 5696  // zero u[0..5696): keys+barriers+stats (0u == 0.0f)
#define STAT_OFF 4672
#define CTAB_OFF 5696
#define BMIN_OFF 256
#define BMAX_OFF 2304
#define TAB_OFF 4352
#define SSLOT_OFF 4992

// monotonic float<->uint order mapping (no NaNs in randn inputs)
__device__ __forceinline__ unsigned fkey(float f) {
  unsigned u = __float_as_uint(f);
  return u ^ (unsigned(int(u) >> 31) | 0x80000000u);
}
__device__ __forceinline__ float funkey(unsigned k) {
  unsigned u = (k & 0x80000000u) ? (k ^ 0x80000000u) : ~k;
  return __uint_as_float(u);
}

// Column `col` of the fixed 3-layer RY/RZ/CNOT unitary (proven numerics).
__device__ __forceinline__ void build_ucol(int col, const float* __restrict__ w,
                                           float* sr, float* si) {
#pragma unroll
  for (int k = 0; k < 16; ++k) { sr[k] = (k == col) ? 1.f : 0.f; si[k] = 0.f; }
#pragma unroll
  for (int l = 0; l < 3; ++l) {
#pragma unroll
    for (int i = 0; i < 4; ++i) {
      const int m = 8 >> i;
      float ryc, rys, rzc, rzs;
      __sincosf(0.5f * w[(l * 4 + i) * 2 + 0], &rys, &ryc);
      __sincosf(0.5f * w[(l * 4 + i) * 2 + 1], &rzs, &rzc);
#pragma unroll
      for (int k = 0; k < 16; ++k) {
        if (!(k & m)) {
          int k1 = k | m;
          float a0r = sr[k], a0i = si[k], a1r = sr[k1], a1i = si[k1];
          sr[k] = ryc * a0r - rys * a1r;
          si[k] = ryc * a0i - rys * a1i;
          sr[k1] = rys * a0r + ryc * a1r;
          si[k1] = rys * a0i + ryc * a1i;
        }
      }
#pragma unroll
      for (int k = 0; k < 16; ++k) {
        float ps = (k & m) ? rzs : -rzs;
        float rr = sr[k], ii = si[k];
        sr[k] = rr * rzc - ii * ps;
        si[k] = rr * ps + ii * rzc;
      }
    }
#pragma unroll
    for (int c = 0; c < 4; ++c) {
      const int mc = 8 >> c;
      const int mt = 8 >> ((c + 1) & 3);
#pragma unroll
      for (int k = 0; k < 16; ++k) {
        if ((k & mc) && !(k & mt)) {
          int k2 = k | mt;
          float tt;
          tt = sr[k]; sr[k] = sr[k2]; sr[k2] = tt;
          tt = si[k]; si[k] = si[k2]; si[k2] = tt;
        }
      }
    }
  }
}

// ===========================================================================
// K0: one block. Zero all barrier/key/stat slots, set min sentinels, build
// tables. Kernel boundary makes everything coherent for `fused`.
// ===========================================================================
__global__ __launch_bounds__(128) void k0_init(const float* __restrict__ w,
                                               const float* __restrict__ fc_w,
                                               float* __restrict__ wsf) {
  int tid = threadIdx.x;
  unsigned* u = (unsigned*)wsf;
  for (int i = tid; i < UZERO_N; i += 128) u[i] = 0u;
  __syncthreads();
  if (tid < 16) {
    float sr[16], si[16];
    build_ucol(tid, w, sr, si);
#pragma unroll
    for (int k = 0; k < 16; ++k) {
      wsf[CTAB_OFF + tid * 16 + k] = sr[k];
      wsf[CTAB_OFF + 256 + tid * 16 + k] = si[k];
    }
  } else if (tid < 32) {
    u[MK_OFF + (tid - 16) * 32] = 0xFFFFFFFFu;  // min-key sentinels
  } else if (tid >= 64 && tid < 128) {
    // AT[k][j] = sum_i fc_w[j][i] * Zparity(k,i)
    int e = tid - 64, k = e >> 2, j = e & 3;
    float s = 0.f;
#pragma unroll
    for (int i = 0; i < 4; ++i)
      s += fc_w[j * 4 + i] * ((k & (8 >> i)) ? -1.f : 1.f);
    wsf[CTAB_OFF + 512 + k * 4 + j] = s;
  }
}

// Hierarchical grid barrier, RELAXED-ONLY. One spinner per block; s_sleep
// backoff. Proven correct in R8 (absmax 0.0156).
__device__ __forceinline__ void grid_barrier(unsigned* __restrict__ leaf,
                                             unsigned* __restrict__ flag,
                                             unsigned* __restrict__ root) {
  __syncthreads();  // compiler emits s_waitcnt vmcnt(0) before s_barrier
  if (threadIdx.x == 0) {
    const int l = (int)(blockIdx.x >> 5);  // 32 blocks per leaf
    unsigned p = __hip_atomic_fetch_add(leaf + l * 32, 1u, __ATOMIC_RELAXED,
                                        __HIP_MEMORY_SCOPE_AGENT);
    if (p == 31u) {  // last arrival at this leaf
      unsigned q = __hip_atomic_fetch_add(root, 1u, __ATOMIC_RELAXED,
                                          __HIP_MEMORY_SCOPE_AGENT);
      if (q == (unsigned)(NLEAF - 1)) {  // last leaf: release everyone
#pragma unroll
        for (int f = 0; f < NLEAF; ++f)
          __hip_atomic_store(flag + f * 32, 1u, __ATOMIC_RELAXED,
                             __HIP_MEMORY_SCOPE_AGENT);
      }
    }
    while (__hip_atomic_load(flag + l * 32, __ATOMIC_RELAXED,
                             __HIP_MEMORY_SCOPE_AGENT) == 0u)
      __builtin_amdgcn_s_sleep(16);
    asm volatile("" ::: "memory");  // no compiler hoisting past the spin
  }
  __syncthreads();
}

// Single-sample fused circuit+linear: o = A|U v|^2 (bias cancels in BN).
__device__ __forceinline__ void qfc_one(const float* __restrict__ tab,
                                        const float* c, const float* s,
                                        float* o) {
  const float* __restrict__ Ur = tab;
  const float* __restrict__ Ui = tab + 256;
  const float* __restrict__ At = tab + 512;
  float A01[4] = {c[0] * c[1], c[0] * s[1], s[0] * c[1], s[0] * s[1]};
  float A23[4] = {c[2] * c[3], c[2] * s[3], s[2] * c[3], s[2] * s[3]};
  float yr[16], yi[16];
#pragma unroll
  for (int k = 0; k < 16; ++k) { yr[k] = yi[k] = 0.f; }
#pragma unroll
  for (int a = 0; a < 16; ++a) {
    float va = A01[a >> 2] * A23[a & 3];
#pragma unroll
    for (int k = 0; k < 16; ++k) {
      yr[k] = fmaf(Ur[a * 16 + k], va, yr[k]);
      yi[k] = fmaf(Ui[a * 16 + k], va, yi[k]);
    }
  }
#pragma unroll
  for (int j = 0; j < 4; ++j) o[j] = 0.f;
#pragma unroll
  for (int k = 0; k < 16; ++k) {
    float p = fmaf(yr[k], yr[k], yi[k] * yi[k]);
#pragma unroll
    for (int j = 0; j < 4; ++j) o[j] = fmaf(At[k * 4 + j], p, o[j]);
  }
}

// ===========================================================================
// Barrier kernel. x read once, out written once post-BN. Consumer-side
// atomic reads are SINGLE-WAVE per block (R8 lesson: atomic loads are
// RMW-priced; 2M of them = 500 MB of HBM traffic).
// ===========================================================================
__global__ __launch_bounds__(NT, 4) void fused(
    const float* __restrict__ x, float* __restrict__ wsf,
    const float* __restrict__ gamma, const float* __restrict__ beta,
    float* __restrict__ out, int B) {
  const int tid = threadIdx.x;
  const int gtid = blockIdx.x * NT + tid;
  const int H = NBLK * NT;  // 262144
  const int wv = tid >> 6, ln = tid & 63;
  unsigned* __restrict__ u = (unsigned*)wsf;
  const float* __restrict__ tab = wsf + CTAB_OFF;
  float* __restrict__ stat = wsf + STAT_OFF;
  __shared__ float smn[4], smx[4];
  __shared__ float red[4][8];
  __shared__ float sbc[2];
  __shared__ float sst[8];

  // ---- Phase 1: load rows (keep in regs), block min/max -> sharded atomics
  const int s0 = gtid, s1 = gtid + H;
  const bool h0 = s0 < B, h1 = s1 < B;
  float4 xa = h0 ? *(const float4*)(x + (size_t)s0 * 16) : make_float4(0, 0, 0, 0);
  float4 xb = h1 ? *(const float4*)(x + (size_t)s1 * 16) : make_float4(0, 0, 0, 0);

  float fmn = __builtin_inff(), fmx = -__builtin_inff();
  if (h0) {
    fmn = fminf(fminf(xa.x, xa.y), fminf(xa.z, xa.w));
    fmx = fmaxf(fmaxf(xa.x, xa.y), fmaxf(xa.z, xa.w));
  }
  if (h1) {
    fmn = fminf(fmn, fminf(fminf(xb.x, xb.y), fminf(xb.z, xb.w)));
    fmx = fmaxf(fmx, fmaxf(fmaxf(xb.x, xb.y), fmaxf(xb.z, xb.w)));
  }
#pragma unroll
  for (int d = 32; d; d >>= 1) {
    fmn = fminf(fmn, __shfl_down(fmn, d));
    fmx = fmaxf(fmx, __shfl_down(fmx, d));
  }
  if (ln == 0) { smn[wv] = fmn; smx[wv] = fmx; }
  __syncthreads();
  if (tid == 0) {
    float bm = fminf(fminf(smn[0], smn[1]), fminf(smn[2], smn[3]));
    float bM = fmaxf(fmaxf(smx[0], smx[1]), fmaxf(smx[2], smx[3]));
    const int sh = (int)(blockIdx.x & (MKSH - 1));
    atomicMin(u + MK_OFF + sh * 32, fkey(bm));
    atomicMax(u + MK_OFF + sh * 32 + 16, fkey(bM));
  }

  grid_barrier(u + LEAFA_OFF, u + FLAGA_OFF, u + ROOTA_OFF);

  // ---- Phase 2: min/max shard read by 32 lanes of wave 0 ONLY (32 atomic
  // loads/block), group shfl_xor reduce, LDS broadcast.
  if (tid < 32) {
    unsigned k;
    if (tid < 16)
      k = __hip_atomic_load(u + MK_OFF + tid * 32, __ATOMIC_RELAXED,
                            __HIP_MEMORY_SCOPE_AGENT);
    else
      k = __hip_atomic_load(u + MK_OFF + (tid - 16) * 32 + 16, __ATOMIC_RELAXED,
                            __HIP_MEMORY_SCOPE_AGENT);
#pragma unroll
    for (int d = 8; d; d >>= 1) {  // xor of {8,4,2,1} stays within each 16-group
      unsigned p = __shfl_xor(k, d);
      k = (tid < 16) ? ((p < k) ? p : k) : ((p > k) ? p : k);
    }
    if (tid == 0) sbc[0] = funkey(k);
    if (tid == 16) sbc[1] = funkey(k);
  }
  __syncthreads();
  const float gm = sbc[0], gM = sbc[1];
  const float ssc = TWO_PI_F * 0.5f / (gM - gm + 1e-8f);  // half-angle scale

  float a0[4] = {xa.x, xa.y, xa.z, xa.w};
  float a1[4] = {xb.x, xb.y, xb.z, xb.w};
  float c0[4], sn0[4], c1[4], sn1[4];
#pragma unroll
  for (int i = 0; i < 4; ++i) {
    __sincosf((a0[i] - gm) * ssc, &sn0[i], &c0[i]);
    __sincosf((a1[i] - gm) * ssc, &sn1[i], &c1[i]);
  }
  float o0[4], o1[4];
  qfc_one(tab, c0, sn0, o0);  // sequential pair keeps peak VGPRs < 128 cap
  qfc_one(tab, c1, sn1, o1);

  float vals[8];
#pragma unroll
  for (int j = 0; j < 4; ++j) {
    float v0 = h0 ? o0[j] : 0.f, v1 = h1 ? o1[j] : 0.f;
    vals[j] = v0 + v1;
    vals[4 + j] = fmaf(v0, v0, v1 * v1);
  }
#pragma unroll
  for (int j = 0; j < 8; ++j) {
#pragma unroll
    for (int d = 32; d; d >>= 1) vals[j] += __shfl_down(vals[j], d);
  }
  if (ln == 0) {
#pragma unroll
    for (int j = 0; j < 8; ++j) red[wv][j] = vals[j];
  }
  __syncthreads();
  if (tid < 8) {
    const int sh = (int)(blockIdx.x & (STSH - 1));
    atomicAdd(stat + sh * 16 + tid,
              red[0][tid] + red[1][tid] + red[2][tid] + red[3][tid]);
  }

  grid_barrier(u + LEAFB_OFF, u + FLAGB_OFF, u + ROOTB_OFF);

  // ---- Phase 3: stat shard read by wave 0 ONLY (64 atomic loads/block:
  // lane t -> shard s=t>>3, j=t&7), shfl_down sum over shards, LDS broadcast.
  if (tid < 64) {
    int s = tid >> 3, j = tid & 7;
    float v = __hip_atomic_load(stat + s * 16 + j, __ATOMIC_RELAXED,
                                __HIP_MEMORY_SCOPE_AGENT);
    v += __shfl_down(v, 32);  // s+4, same j
    v += __shfl_down(v, 16);  // s+2
    v += __shfl_down(v, 8);   // s+1
    if (tid < 8) sst[tid] = v;
  }
  __syncthreads();

  const float inv = 1.0f / (float)B;
  float sc[4], sh[4];
#pragma unroll
  for (int j = 0; j < 4; ++j) {
    float mean = sst[j] * inv;
    float var = sst[4 + j] * inv - mean * mean;
    float is = rsqrtf(var + BN_EPS_F);
    sc[j] = gamma[j] * is;
    sh[j] = beta[j] - mean * sc[j];
  }
  if (h0)
    *(float4*)(out + (size_t)s0 * 4) =
        make_float4(fmaf(o0[0], sc[0], sh[0]), fmaf(o0[1], sc[1], sh[1]),
                    fmaf(o0[2], sc[2], sh[2]), fmaf(o0[3], sc[3], sh[3]));
  if (h1)
    *(float4*)(out + (size_t)s1 * 4) =
        make_float4(fmaf(o1[0], sc[0], sh[0]), fmaf(o1[1], sc[1], sh[1]),
                    fmaf(o1[2], sc[2], sh[2]), fmaf(o1[3], sc[3], sh[3]));
}

// ===========================================================================
// Fallback: the proven 111.3 µs 3-kernel pipeline (runs only if the
// barrier path is gated off).
// ===========================================================================
__global__ __launch_bounds__(NT) void k1_scan_tab(const float* __restrict__ x,
                                                  const float* __restrict__ w,
                                                  const float* __restrict__ fc_w,
                                                  float* __restrict__ wsf, int B) {
  int r = blockIdx.x * NT + threadIdx.x;
  float fmn = __builtin_inff(), fmx = -__builtin_inff();
  if (r < B) {
    float4 v = *(const float4*)(x + (size_t)r * 16);
    fmn = fminf(fminf(v.x, v.y), fminf(v.z, v.w));
    fmx = fmaxf(fmaxf(v.x, v.y), fmaxf(v.z, v.w));
  }
#pragma unroll
  for (int d = 32; d; d >>= 1) {
    fmn = fminf(fmn, __shfl_down(fmn, d));
    fmx = fmaxf(fmx, __shfl_down(fmx, d));
  }
  __shared__ float smn[4], smx[4];
  int wv = threadIdx.x >> 6, ln = threadIdx.x & 63;
  if (ln == 0) { smn[wv] = fmn; smx[wv] = fmx; }
  __syncthreads();
  if (threadIdx.x == 0) {
    wsf[BMIN_OFF + blockIdx.x] =
        fminf(fminf(smn[0], smn[1]), fminf(smn[2], smn[3]));
    wsf[BMAX_OFF + blockIdx.x] =
        fmaxf(fmaxf(smx[0], smx[1]), fmaxf(smx[2], smx[3]));
  }
  if (blockIdx.x == 0) {
    int tid = threadIdx.x;
    if (tid < 16) {
      float sr[16], si[16];
      build_ucol(tid, w, sr, si);
#pragma unroll
      for (int k = 0; k < 16; ++k) {
        wsf[TAB_OFF + tid * 16 + k] = sr[k];
        wsf[TAB_OFF + 256 + tid * 16 + k] = si[k];
      }
    } else if (tid == 16) {
      for (int k = 0; k < 16; ++k)
        for (int j = 0; j < 4; ++j) {
          float s = 0.f;
          for (int i = 0; i < 4; ++i)
            s += fc_w[j * 4 + i] * ((k & (8 >> i)) ? -1.f : 1.f);
          wsf[TAB_OFF + 512 + k * 4 + j] = s;
        }
    }
  }
}

__device__ __forceinline__ void qfc_pair(const float* __restrict__ tab,
                                         const float* c0, const float* s0,
                                         const float* c1, const float* s1,
                                         float* o0, float* o1) {
  const float* __restrict__ Ur = tab;
  const float* __restrict__ Ui = tab + 256;
  const float* __restrict__ At = tab + 512;
  float A01_0[4] = {c0[0] * c0[1], c0[0] * s0[1], s0[0] * c0[1], s0[0] * s0[1]};
  float A23_0[4] = {c0[2] * c0[3], c0[2] * s0[3], s0[2] * c0[3], s0[2] * s0[3]};
  float A01_1[4] = {c1[0] * c1[1], c1[0] * s1[1], s1[0] * c1[1], s1[0] * s1[1]};
  float A23_1[4] = {c1[2] * c1[3], c1[2] * s1[3], s1[2] * c1[3], s1[2] * s1[3]};
  float yr0[16], yi0[16], yr1[16], yi1[16];
#pragma unroll
  for (int k = 0; k < 16; ++k) { yr0[k] = yi0[k] = yr1[k] = yi1[k] = 0.f; }
#pragma unroll
  for (int a = 0; a < 16; ++a) {
    float va0 = A01_0[a >> 2] * A23_0[a & 3];
    float va1 = A01_1[a >> 2] * A23_1[a & 3];
#pragma unroll
    for (int k = 0; k < 16; ++k) {
      float ur = Ur[a * 16 + k], ui = Ui[a * 16 + k];
      yr0[k] = fmaf(ur, va0, yr0[k]);
      yi0[k] = fmaf(ui, va0, yi0[k]);
      yr1[k] = fmaf(ur, va1, yr1[k]);
      yi1[k] = fmaf(ui, va1, yi1[k]);
    }
  }
#pragma unroll
  for (int j = 0; j < 4; ++j) { o0[j] = 0.f; o1[j] = 0.f; }
#pragma unroll
  for (int k = 0; k < 16; ++k) {
    float p0 = fmaf(yr0[k], yr0[k], yi0[k] * yi0[k]);
    float p1 = fmaf(yr1[k], yr1[k], yi1[k] * yi1[k]);
#pragma unroll
    for (int j = 0; j < 4; ++j) {
      float av = At[k * 4 + j];
      o0[j] = fmaf(av, p0, o0[j]);
      o1[j] = fmaf(av, p1, o1[j]);
    }
  }
}

__global__ __launch_bounds__(NT) void k2_main(const float* __restrict__ x,
                                              const float* __restrict__ wsf,
                                              float* __restrict__ sslot,
                                              float* __restrict__ out, int B) {
  const int tid = threadIdx.x;
  const int gtid = blockIdx.x * NT + tid;
  const int H = NB2 * NT;
  const int wv = tid >> 6, ln = tid & 63;
  const float* __restrict__ tab = wsf + TAB_OFF;

  float gm = __builtin_inff(), gM = -__builtin_inff();
#pragma unroll
  for (int q = 0; q < NB1 / 64; ++q) {
    int i = ln + q * 64;
    gm = fminf(gm, wsf[BMIN_OFF + i]);
    gM = fmaxf(gM, wsf[BMAX_OFF + i]);
  }
#pragma unroll
  for (int d = 32; d; d >>= 1) {
    gm = fminf(gm, __shfl_down(gm, d));
    gM = fmaxf(gM, __shfl_down(gM, d));
  }
  gm = __shfl(gm, 0);
  gM = __shfl(gM, 0);
  const float ssc = TWO_PI_F * 0.5f / (gM - gm + 1e-8f);

  const int s0 = gtid, s1 = gtid + H;
  const bool h0 = s0 < B, h1 = s1 < B;
  float4 xa = h0 ? *(const float4*)(x + (size_t)s0 * 16) : make_float4(0, 0, 0, 0);
  float4 xb = h1 ? *(const float4*)(x + (size_t)s1 * 16) : make_float4(0, 0, 0, 0);

  float a0[4] = {xa.x, xa.y, xa.z, xa.w};
  float a1[4] = {xb.x, xb.y, xb.z, xb.w};
  float c0[4], sn0[4], c1[4], sn1[4];
#pragma unroll
  for (int i = 0; i < 4; ++i) {
    __sincosf((a0[i] - gm) * ssc, &sn0[i], &c0[i]);
    __sincosf((a1[i] - gm) * ssc, &sn1[i], &c1[i]);
  }
  float o0[4], o1[4];
  qfc_pair(tab, c0, sn0, c1, sn1, o0, o1);

  if (h0)
    *(float4*)(out + (size_t)s0 * 4) = make_float4(o0[0], o0[1], o0[2], o0[3]);
  if (h1)
    *(float4*)(out + (size_t)s1 * 4) = make_float4(o1[0], o1[1], o1[2], o1[3]);

  float vals[8];
#pragma unroll
  for (int j = 0; j < 4; ++j) {
    float v0 = h0 ? o0[j] : 0.f, v1 = h1 ? o1[j] : 0.f;
    vals[j] = v0 + v1;
    vals[4 + j] = fmaf(v0, v0, v1 * v1);
  }
#pragma unroll
  for (int j = 0; j < 8; ++j) {
#pragma unroll
    for (int d = 32; d; d >>= 1) vals[j] += __shfl_down(vals[j], d);
  }
  __shared__ float red[4][8];
  if (ln == 0) {
#pragma unroll
    for (int j = 0; j < 8; ++j) red[wv][j] = vals[j];
  }
  __syncthreads();
  if (tid < 8) {
    sslot[blockIdx.x * 8 + tid] =
        red[0][tid] + red[1][tid] + red[2][tid] + red[3][tid];
  }
}

__global__ __launch_bounds__(NT) void k3_final(float* __restrict__ out,
                                               const float* __restrict__ sslot,
                                               const float* __restrict__ gamma,
                                               const float* __restrict__ beta,
                                               int B) {
  const int tid = threadIdx.x;
  const int gtid = blockIdx.x * NT + tid;
  const int H = NB2 * NT;
  const int ln = tid & 63;

  float v = 0.f;
#pragma unroll
  for (int k = 0; k < (NB2 * 8) / 64; ++k) v += sslot[k * 64 + ln];
#pragma unroll
  for (int d = 32; d >= 8; d >>= 1) v += __shfl_down(v, d);
  float st[8];
#pragma unroll
  for (int j = 0; j < 8; ++j) st[j] = __shfl(v, j);

  const float inv = 1.0f / (float)B;
  float sc[4], sh[4];
#pragma unroll
  for (int j = 0; j < 4; ++j) {
    float mean = st[j] * inv;
    float var = st[4 + j] * inv - mean * mean;
    float is = rsqrtf(var + BN_EPS_F);
    sc[j] = gamma[j] * is;
    sh[j] = beta[j] - mean * sc[j];
  }
#pragma unroll
  for (int p = 0; p < 2; ++p) {
    int s = gtid + p * H;
    if (s < B) {
      float4 q = *(float4*)(out + (size_t)s * 4);
      *(float4*)(out + (size_t)s * 4) =
          make_float4(fmaf(q.x, sc[0], sh[0]), fmaf(q.y, sc[1], sh[1]),
                      fmaf(q.z, sc[2], sh[2]), fmaf(q.w, sc[3], sh[3]));
    }
  }
}

extern "C" void kernel_launch(void* const* d_in, const int* in_sizes, int n_in,
                              void* d_out, int out_size, void* d_ws, size_t ws_size,
                              hipStream_t stream) {
  const float* x = (const float*)d_in[0];
  const float* w = (const float*)d_in[1];
  const float* fc_w = (const float*)d_in[2];
  const float* gamma = (const float*)d_in[4];
  const float* beta = (const float*)d_in[5];
  float* out = (float*)d_out;
  float* wsf = (float*)d_ws;
  int B = in_sizes[0] / 16;

  k0_init<<<1, 128, 0, stream>>>(w, fc_w, wsf);

  // Host-side, capture-safe gate: only use the barrier kernel if the runtime
  // certifies full-grid co-residency (the hand-rolled barrier requires it).
  static int coop_state = -1;  // -1 unknown, 0 no, 1 yes
  if (coop_state < 0) {
    int dev = 0;
    (void)hipGetDevice(&dev);
    int ncu = 0;
    (void)hipDeviceGetAttribute(&ncu, hipDeviceAttributeMultiprocessorCount, dev);
    int per_cu = 0;
    (void)hipOccupancyMaxActiveBlocksPerMultiprocessor(&per_cu,
                                                       (const void*)fused, NT, 0);
    coop_state =
        (ncu > 0 && per_cu > 0 && (long long)per_cu * ncu >= NBLK) ? 1 : 0;
  }

  if (coop_state == 1 && B <= 2 * NBLK * NT) {
    fused<<<NBLK, NT, 0, stream>>>(x, wsf, gamma, beta, out, B);
  } else {
    k1_scan_tab<<<NB1, NT, 0, stream>>>(x, w, fc_w, wsf, B);
    k2_main<<<NB2, NT, 0, stream>>>(x, wsf, wsf + SSLOT_OFF, out, B);
    k3_final<<<NB2, NT, 0, stream>>>(out, wsf + SSLOT_OFF, gamma, beta, B);
  }
}

// Round 10
// 117.288 us; speedup vs baseline: 1.0072x; 1.0072x over previous
//
#include <hip/hip_runtime.h>
#include <math.h>

#define TWO_PI_F 6.28318530717958647692f
#define BN_EPS_F 1e-5f

// barrier-kernel config: 1024 blocks * 256 thr = 4 blocks/CU on 256 CUs
#define NBLK 1024
#define NT 256
#define NLEAF 32   // barrier tree: 32 leaves x 32 blocks
#define MKSH 16    // min/max shards (write side)
#define STSH 8     // BN stat shards

// fallback (proven 3-kernel) config
#define NB1 2048
#define NB2 1024

// ---------------------------------------------------------------------------
// Workspace layout (uint offsets on u = (unsigned*)wsf). R9 lesson: the
// hand-rolled barrier kernel carries ~400 MB of deterministic mystery traffic
// (NOT spins, NOT fences, NOT consumer atomic loads). This round: ONE barrier
// only (min/max); BN finalize moves to a separate kernel k3s where stats are
// read with PLAIN coherent loads after the kernel boundary.
//   MK     : u[s*32] min key, u[s*32+16] max key, s<16            [0..512)
//   LEAFA  : u[512  + l*32]  leaf counters                         [512..1536)
//   FLAGA  : u[1536 + l*32]  per-leaf release flags                [1536..2560)
//   ROOTA  : u[2560]                                               [2560..2592)
// float offsets:
//   STAT   : wsf[4672 + s*16 + j], s<8, j<8 (atomicAdd shards)     [4672..4800)
//   CTAB   : UrT[256] | UiT[256] | AT[64]                          [5696..6272)
// Fallback keeps its proven layout (paths mutually exclusive).
// ---------------------------------------------------------------------------
#define MK_OFF 0
#define LEAFA_OFF 512
#define FLAGA_OFF 1536
#define ROOTA_OFF 2560
#define UZERO_N 5696  // zero u[0..5696): keys+barrier+stats (0u == 0.0f)
#define STAT_OFF 4672
#define CTAB_OFF 5696
#define BMIN_OFF 256
#define BMAX_OFF 2304
#define TAB_OFF 4352
#define SSLOT_OFF 4992

// monotonic float<->uint order mapping (no NaNs in randn inputs)
__device__ __forceinline__ unsigned fkey(float f) {
  unsigned u = __float_as_uint(f);
  return u ^ (unsigned(int(u) >> 31) | 0x80000000u);
}
__device__ __forceinline__ float funkey(unsigned k) {
  unsigned u = (k & 0x80000000u) ? (k ^ 0x80000000u) : ~k;
  return __uint_as_float(u);
}

// Column `col` of the fixed 3-layer RY/RZ/CNOT unitary (proven numerics).
__device__ __forceinline__ void build_ucol(int col, const float* __restrict__ w,
                                           float* sr, float* si) {
#pragma unroll
  for (int k = 0; k < 16; ++k) { sr[k] = (k == col) ? 1.f : 0.f; si[k] = 0.f; }
#pragma unroll
  for (int l = 0; l < 3; ++l) {
#pragma unroll
    for (int i = 0; i < 4; ++i) {
      const int m = 8 >> i;
      float ryc, rys, rzc, rzs;
      __sincosf(0.5f * w[(l * 4 + i) * 2 + 0], &rys, &ryc);
      __sincosf(0.5f * w[(l * 4 + i) * 2 + 1], &rzs, &rzc);
#pragma unroll
      for (int k = 0; k < 16; ++k) {
        if (!(k & m)) {
          int k1 = k | m;
          float a0r = sr[k], a0i = si[k], a1r = sr[k1], a1i = si[k1];
          sr[k] = ryc * a0r - rys * a1r;
          si[k] = ryc * a0i - rys * a1i;
          sr[k1] = rys * a0r + ryc * a1r;
          si[k1] = rys * a0i + ryc * a1i;
        }
      }
#pragma unroll
      for (int k = 0; k < 16; ++k) {
        float ps = (k & m) ? rzs : -rzs;
        float rr = sr[k], ii = si[k];
        sr[k] = rr * rzc - ii * ps;
        si[k] = rr * ps + ii * rzc;
      }
    }
#pragma unroll
    for (int c = 0; c < 4; ++c) {
      const int mc = 8 >> c;
      const int mt = 8 >> ((c + 1) & 3);
#pragma unroll
      for (int k = 0; k < 16; ++k) {
        if ((k & mc) && !(k & mt)) {
          int k2 = k | mt;
          float tt;
          tt = sr[k]; sr[k] = sr[k2]; sr[k2] = tt;
          tt = si[k]; si[k] = si[k2]; si[k2] = tt;
        }
      }
    }
  }
}

// ===========================================================================
// K0: one block. Zero barrier/key/stat slots, set min sentinels, build tables.
// ===========================================================================
__global__ __launch_bounds__(128) void k0_init(const float* __restrict__ w,
                                               const float* __restrict__ fc_w,
                                               float* __restrict__ wsf) {
  int tid = threadIdx.x;
  unsigned* u = (unsigned*)wsf;
  for (int i = tid; i < UZERO_N; i += 128) u[i] = 0u;
  __syncthreads();
  if (tid < 16) {
    float sr[16], si[16];
    build_ucol(tid, w, sr, si);
#pragma unroll
    for (int k = 0; k < 16; ++k) {
      wsf[CTAB_OFF + tid * 16 + k] = sr[k];
      wsf[CTAB_OFF + 256 + tid * 16 + k] = si[k];
    }
  } else if (tid < 32) {
    u[MK_OFF + (tid - 16) * 32] = 0xFFFFFFFFu;  // min-key sentinels
  } else if (tid >= 64 && tid < 128) {
    // AT[k][j] = sum_i fc_w[j][i] * Zparity(k,i)
    int e = tid - 64, k = e >> 2, j = e & 3;
    float s = 0.f;
#pragma unroll
    for (int i = 0; i < 4; ++i)
      s += fc_w[j * 4 + i] * ((k & (8 >> i)) ? -1.f : 1.f);
    wsf[CTAB_OFF + 512 + k * 4 + j] = s;
  }
}

// Hierarchical grid barrier, RELAXED-ONLY (proven correct R8/R9).
__device__ __forceinline__ void grid_barrier(unsigned* __restrict__ leaf,
                                             unsigned* __restrict__ flag,
                                             unsigned* __restrict__ root) {
  __syncthreads();  // compiler emits s_waitcnt vmcnt(0) before s_barrier
  if (threadIdx.x == 0) {
    const int l = (int)(blockIdx.x >> 5);  // 32 blocks per leaf
    unsigned p = __hip_atomic_fetch_add(leaf + l * 32, 1u, __ATOMIC_RELAXED,
                                        __HIP_MEMORY_SCOPE_AGENT);
    if (p == 31u) {
      unsigned q = __hip_atomic_fetch_add(root, 1u, __ATOMIC_RELAXED,
                                          __HIP_MEMORY_SCOPE_AGENT);
      if (q == (unsigned)(NLEAF - 1)) {
#pragma unroll
        for (int f = 0; f < NLEAF; ++f)
          __hip_atomic_store(flag + f * 32, 1u, __ATOMIC_RELAXED,
                             __HIP_MEMORY_SCOPE_AGENT);
      }
    }
    while (__hip_atomic_load(flag + l * 32, __ATOMIC_RELAXED,
                             __HIP_MEMORY_SCOPE_AGENT) == 0u)
      __builtin_amdgcn_s_sleep(16);
    asm volatile("" ::: "memory");
  }
  __syncthreads();
}

// Single-sample fused circuit+linear: o = A|U v|^2 (bias cancels in BN).
__device__ __forceinline__ void qfc_one(const float* __restrict__ tab,
                                        const float* c, const float* s,
                                        float* o) {
  const float* __restrict__ Ur = tab;
  const float* __restrict__ Ui = tab + 256;
  const float* __restrict__ At = tab + 512;
  float A01[4] = {c[0] * c[1], c[0] * s[1], s[0] * c[1], s[0] * s[1]};
  float A23[4] = {c[2] * c[3], c[2] * s[3], s[2] * c[3], s[2] * s[3]};
  float yr[16], yi[16];
#pragma unroll
  for (int k = 0; k < 16; ++k) { yr[k] = yi[k] = 0.f; }
#pragma unroll
  for (int a = 0; a < 16; ++a) {
    float va = A01[a >> 2] * A23[a & 3];
#pragma unroll
    for (int k = 0; k < 16; ++k) {
      yr[k] = fmaf(Ur[a * 16 + k], va, yr[k]);
      yi[k] = fmaf(Ui[a * 16 + k], va, yi[k]);
    }
  }
#pragma unroll
  for (int j = 0; j < 4; ++j) o[j] = 0.f;
#pragma unroll
  for (int k = 0; k < 16; ++k) {
    float p = fmaf(yr[k], yr[k], yi[k] * yi[k]);
#pragma unroll
    for (int j = 0; j < 4; ++j) o[j] = fmaf(At[k * 4 + j], p, o[j]);
  }
}

// ===========================================================================
// fused2: ONE barrier (min/max only). x read once (regs across barrier),
// writes PRE-BN out + 8 sharded stat atomicAdds. No phase-3, no barrier B.
// ===========================================================================
__global__ __launch_bounds__(NT, 4) void fused2(
    const float* __restrict__ x, float* __restrict__ wsf,
    float* __restrict__ out, int B) {
  const int tid = threadIdx.x;
  const int gtid = blockIdx.x * NT + tid;
  const int H = NBLK * NT;  // 262144
  const int wv = tid >> 6, ln = tid & 63;
  unsigned* __restrict__ u = (unsigned*)wsf;
  const float* __restrict__ tab = wsf + CTAB_OFF;
  float* __restrict__ stat = wsf + STAT_OFF;
  __shared__ float smn[4], smx[4];
  __shared__ float red[4][8];
  __shared__ float sbc[2];

  // ---- Phase 1: load rows (keep in regs), block min/max -> sharded atomics
  const int s0 = gtid, s1 = gtid + H;
  const bool h0 = s0 < B, h1 = s1 < B;
  float4 xa = h0 ? *(const float4*)(x + (size_t)s0 * 16) : make_float4(0, 0, 0, 0);
  float4 xb = h1 ? *(const float4*)(x + (size_t)s1 * 16) : make_float4(0, 0, 0, 0);

  float fmn = __builtin_inff(), fmx = -__builtin_inff();
  if (h0) {
    fmn = fminf(fminf(xa.x, xa.y), fminf(xa.z, xa.w));
    fmx = fmaxf(fmaxf(xa.x, xa.y), fmaxf(xa.z, xa.w));
  }
  if (h1) {
    fmn = fminf(fmn, fminf(fminf(xb.x, xb.y), fminf(xb.z, xb.w)));
    fmx = fmaxf(fmx, fmaxf(fmaxf(xb.x, xb.y), fmaxf(xb.z, xb.w)));
  }
#pragma unroll
  for (int d = 32; d; d >>= 1) {
    fmn = fminf(fmn, __shfl_down(fmn, d));
    fmx = fmaxf(fmx, __shfl_down(fmx, d));
  }
  if (ln == 0) { smn[wv] = fmn; smx[wv] = fmx; }
  __syncthreads();
  if (tid == 0) {
    float bm = fminf(fminf(smn[0], smn[1]), fminf(smn[2], smn[3]));
    float bM = fmaxf(fmaxf(smx[0], smx[1]), fmaxf(smx[2], smx[3]));
    const int sh = (int)(blockIdx.x & (MKSH - 1));
    atomicMin(u + MK_OFF + sh * 32, fkey(bm));
    atomicMax(u + MK_OFF + sh * 32 + 16, fkey(bM));
  }

  grid_barrier(u + LEAFA_OFF, u + FLAGA_OFF, u + ROOTA_OFF);

  // ---- Phase 2: min/max shard read (32 atomic loads/block), compute,
  // write pre-BN out, stat partial atomics. DONE (no second barrier).
  if (tid < 32) {
    unsigned k;
    if (tid < 16)
      k = __hip_atomic_load(u + MK_OFF + tid * 32, __ATOMIC_RELAXED,
                            __HIP_MEMORY_SCOPE_AGENT);
    else
      k = __hip_atomic_load(u + MK_OFF + (tid - 16) * 32 + 16, __ATOMIC_RELAXED,
                            __HIP_MEMORY_SCOPE_AGENT);
#pragma unroll
    for (int d = 8; d; d >>= 1) {  // xor {8,4,2,1} stays within each 16-group
      unsigned p = __shfl_xor(k, d);
      k = (tid < 16) ? ((p < k) ? p : k) : ((p > k) ? p : k);
    }
    if (tid == 0) sbc[0] = funkey(k);
    if (tid == 16) sbc[1] = funkey(k);
  }
  __syncthreads();
  const float gm = sbc[0], gM = sbc[1];
  const float ssc = TWO_PI_F * 0.5f / (gM - gm + 1e-8f);  // half-angle scale

  float a0[4] = {xa.x, xa.y, xa.z, xa.w};
  float a1[4] = {xb.x, xb.y, xb.z, xb.w};
  float c0[4], sn0[4], c1[4], sn1[4];
#pragma unroll
  for (int i = 0; i < 4; ++i) {
    __sincosf((a0[i] - gm) * ssc, &sn0[i], &c0[i]);
    __sincosf((a1[i] - gm) * ssc, &sn1[i], &c1[i]);
  }
  float o0[4], o1[4];
  qfc_one(tab, c0, sn0, o0);
  qfc_one(tab, c1, sn1, o1);

  if (h0)
    *(float4*)(out + (size_t)s0 * 4) = make_float4(o0[0], o0[1], o0[2], o0[3]);
  if (h1)
    *(float4*)(out + (size_t)s1 * 4) = make_float4(o1[0], o1[1], o1[2], o1[3]);

  float vals[8];
#pragma unroll
  for (int j = 0; j < 4; ++j) {
    float v0 = h0 ? o0[j] : 0.f, v1 = h1 ? o1[j] : 0.f;
    vals[j] = v0 + v1;
    vals[4 + j] = fmaf(v0, v0, v1 * v1);
  }
#pragma unroll
  for (int j = 0; j < 8; ++j) {
#pragma unroll
    for (int d = 32; d; d >>= 1) vals[j] += __shfl_down(vals[j], d);
  }
  if (ln == 0) {
#pragma unroll
    for (int j = 0; j < 8; ++j) red[wv][j] = vals[j];
  }
  __syncthreads();
  if (tid < 8) {
    const int sh = (int)(blockIdx.x & (STSH - 1));
    atomicAdd(stat + sh * 16 + tid,
              red[0][tid] + red[1][tid] + red[2][tid] + red[3][tid]);
  }
}

// ===========================================================================
// k3s: after kernel boundary, PLAIN coherent loads of the 8x8 stat shards,
// reduce, BN finalize out in place (2 float4s/thread).
// ===========================================================================
__global__ __launch_bounds__(NT) void k3s(float* __restrict__ out,
                                          const float* __restrict__ wsf,
                                          const float* __restrict__ gamma,
                                          const float* __restrict__ beta,
                                          int B) {
  const int tid = threadIdx.x;
  const int gtid = blockIdx.x * NT + tid;
  const int H = NB2 * NT;
  const float* __restrict__ stat = wsf + STAT_OFF;
  __shared__ float sst[8];

  if (tid < 64) {
    int s = tid >> 3, j = tid & 7;
    float v = stat[s * 16 + j];  // plain load, coherent via kernel boundary
    v += __shfl_down(v, 32);     // s+4, same j
    v += __shfl_down(v, 16);     // s+2
    v += __shfl_down(v, 8);      // s+1
    if (tid < 8) sst[tid] = v;
  }
  __syncthreads();

  const float inv = 1.0f / (float)B;
  float sc[4], sh[4];
#pragma unroll
  for (int j = 0; j < 4; ++j) {
    float mean = sst[j] * inv;
    float var = sst[4 + j] * inv - mean * mean;
    float is = rsqrtf(var + BN_EPS_F);
    sc[j] = gamma[j] * is;
    sh[j] = beta[j] - mean * sc[j];
  }
#pragma unroll
  for (int p = 0; p < 2; ++p) {
    int s = gtid + p * H;
    if (s < B) {
      float4 q = *(float4*)(out + (size_t)s * 4);
      *(float4*)(out + (size_t)s * 4) =
          make_float4(fmaf(q.x, sc[0], sh[0]), fmaf(q.y, sc[1], sh[1]),
                      fmaf(q.z, sc[2], sh[2]), fmaf(q.w, sc[3], sh[3]));
    }
  }
}

// ===========================================================================
// Fallback: the proven 111.3 µs 3-kernel pipeline.
// ===========================================================================
__global__ __launch_bounds__(NT) void k1_scan_tab(const float* __restrict__ x,
                                                  const float* __restrict__ w,
                                                  const float* __restrict__ fc_w,
                                                  float* __restrict__ wsf, int B) {
  int r = blockIdx.x * NT + threadIdx.x;
  float fmn = __builtin_inff(), fmx = -__builtin_inff();
  if (r < B) {
    float4 v = *(const float4*)(x + (size_t)r * 16);
    fmn = fminf(fminf(v.x, v.y), fminf(v.z, v.w));
    fmx = fmaxf(fmaxf(v.x, v.y), fmaxf(v.z, v.w));
  }
#pragma unroll
  for (int d = 32; d; d >>= 1) {
    fmn = fminf(fmn, __shfl_down(fmn, d));
    fmx = fmaxf(fmx, __shfl_down(fmx, d));
  }
  __shared__ float smn[4], smx[4];
  int wv = threadIdx.x >> 6, ln = threadIdx.x & 63;
  if (ln == 0) { smn[wv] = fmn; smx[wv] = fmx; }
  __syncthreads();
  if (threadIdx.x == 0) {
    wsf[BMIN_OFF + blockIdx.x] =
        fminf(fminf(smn[0], smn[1]), fminf(smn[2], smn[3]));
    wsf[BMAX_OFF + blockIdx.x] =
        fmaxf(fmaxf(smx[0], smx[1]), fmaxf(smx[2], smx[3]));
  }
  if (blockIdx.x == 0) {
    int tid = threadIdx.x;
    if (tid < 16) {
      float sr[16], si[16];
      build_ucol(tid, w, sr, si);
#pragma unroll
      for (int k = 0; k < 16; ++k) {
        wsf[TAB_OFF + tid * 16 + k] = sr[k];
        wsf[TAB_OFF + 256 + tid * 16 + k] = si[k];
      }
    } else if (tid == 16) {
      for (int k = 0; k < 16; ++k)
        for (int j = 0; j < 4; ++j) {
          float s = 0.f;
          for (int i = 0; i < 4; ++i)
            s += fc_w[j * 4 + i] * ((k & (8 >> i)) ? -1.f : 1.f);
          wsf[TAB_OFF + 512 + k * 4 + j] = s;
        }
    }
  }
}

__device__ __forceinline__ void qfc_pair(const float* __restrict__ tab,
                                         const float* c0, const float* s0,
                                         const float* c1, const float* s1,
                                         float* o0, float* o1) {
  const float* __restrict__ Ur = tab;
  const float* __restrict__ Ui = tab + 256;
  const float* __restrict__ At = tab + 512;
  float A01_0[4] = {c0[0] * c0[1], c0[0] * s0[1], s0[0] * c0[1], s0[0] * s0[1]};
  float A23_0[4] = {c0[2] * c0[3], c0[2] * s0[3], s0[2] * c0[3], s0[2] * s0[3]};
  float A01_1[4] = {c1[0] * c1[1], c1[0] * s1[1], s1[0] * c1[1], s1[0] * s1[1]};
  float A23_1[4] = {c1[2] * c1[3], c1[2] * s1[3], s1[2] * c1[3], s1[2] * s1[3]};
  float yr0[16], yi0[16], yr1[16], yi1[16];
#pragma unroll
  for (int k = 0; k < 16; ++k) { yr0[k] = yi0[k] = yr1[k] = yi1[k] = 0.f; }
#pragma unroll
  for (int a = 0; a < 16; ++a) {
    float va0 = A01_0[a >> 2] * A23_0[a & 3];
    float va1 = A01_1[a >> 2] * A23_1[a & 3];
#pragma unroll
    for (int k = 0; k < 16; ++k) {
      float ur = Ur[a * 16 + k], ui = Ui[a * 16 + k];
      yr0[k] = fmaf(ur, va0, yr0[k]);
      yi0[k] = fmaf(ui, va0, yi0[k]);
      yr1[k] = fmaf(ur, va1, yr1[k]);
      yi1[k] = fmaf(ui, va1, yi1[k]);
    }
  }
#pragma unroll
  for (int j = 0; j < 4; ++j) { o0[j] = 0.f; o1[j] = 0.f; }
#pragma unroll
  for (int k = 0; k < 16; ++k) {
    float p0 = fmaf(yr0[k], yr0[k], yi0[k] * yi0[k]);
    float p1 = fmaf(yr1[k], yr1[k], yi1[k] * yi1[k]);
#pragma unroll
    for (int j = 0; j < 4; ++j) {
      float av = At[k * 4 + j];
      o0[j] = fmaf(av, p0, o0[j]);
      o1[j] = fmaf(av, p1, o1[j]);
    }
  }
}

__global__ __launch_bounds__(NT) void k2_main(const float* __restrict__ x,
                                              const float* __restrict__ wsf,
                                              float* __restrict__ sslot,
                                              float* __restrict__ out, int B) {
  const int tid = threadIdx.x;
  const int gtid = blockIdx.x * NT + tid;
  const int H = NB2 * NT;
  const int wv = tid >> 6, ln = tid & 63;
  const float* __restrict__ tab = wsf + TAB_OFF;

  float gm = __builtin_inff(), gM = -__builtin_inff();
#pragma unroll
  for (int q = 0; q < NB1 / 64; ++q) {
    int i = ln + q * 64;
    gm = fminf(gm, wsf[BMIN_OFF + i]);
    gM = fmaxf(gM, wsf[BMAX_OFF + i]);
  }
#pragma unroll
  for (int d = 32; d; d >>= 1) {
    gm = fminf(gm, __shfl_down(gm, d));
    gM = fmaxf(gM, __shfl_down(gM, d));
  }
  gm = __shfl(gm, 0);
  gM = __shfl(gM, 0);
  const float ssc = TWO_PI_F * 0.5f / (gM - gm + 1e-8f);

  const int s0 = gtid, s1 = gtid + H;
  const bool h0 = s0 < B, h1 = s1 < B;
  float4 xa = h0 ? *(const float4*)(x + (size_t)s0 * 16) : make_float4(0, 0, 0, 0);
  float4 xb = h1 ? *(const float4*)(x + (size_t)s1 * 16) : make_float4(0, 0, 0, 0);

  float a0[4] = {xa.x, xa.y, xa.z, xa.w};
  float a1[4] = {xb.x, xb.y, xb.z, xb.w};
  float c0[4], sn0[4], c1[4], sn1[4];
#pragma unroll
  for (int i = 0; i < 4; ++i) {
    __sincosf((a0[i] - gm) * ssc, &sn0[i], &c0[i]);
    __sincosf((a1[i] - gm) * ssc, &sn1[i], &c1[i]);
  }
  float o0[4], o1[4];
  qfc_pair(tab, c0, sn0, c1, sn1, o0, o1);

  if (h0)
    *(float4*)(out + (size_t)s0 * 4) = make_float4(o0[0], o0[1], o0[2], o0[3]);
  if (h1)
    *(float4*)(out + (size_t)s1 * 4) = make_float4(o1[0], o1[1], o1[2], o1[3]);

  float vals[8];
#pragma unroll
  for (int j = 0; j < 4; ++j) {
    float v0 = h0 ? o0[j] : 0.f, v1 = h1 ? o1[j] : 0.f;
    vals[j] = v0 + v1;
    vals[4 + j] = fmaf(v0, v0, v1 * v1);
  }
#pragma unroll
  for (int j = 0; j < 8; ++j) {
#pragma unroll
    for (int d = 32; d; d >>= 1) vals[j] += __shfl_down(vals[j], d);
  }
  __shared__ float red[4][8];
  if (ln == 0) {
#pragma unroll
    for (int j = 0; j < 8; ++j) red[wv][j] = vals[j];
  }
  __syncthreads();
  if (tid < 8) {
    sslot[blockIdx.x * 8 + tid] =
        red[0][tid] + red[1][tid] + red[2][tid] + red[3][tid];
  }
}

__global__ __launch_bounds__(NT) void k3_final(float* __restrict__ out,
                                               const float* __restrict__ sslot,
                                               const float* __restrict__ gamma,
                                               const float* __restrict__ beta,
                                               int B) {
  const int tid = threadIdx.x;
  const int gtid = blockIdx.x * NT + tid;
  const int H = NB2 * NT;
  const int ln = tid & 63;

  float v = 0.f;
#pragma unroll
  for (int k = 0; k < (NB2 * 8) / 64; ++k) v += sslot[k * 64 + ln];
#pragma unroll
  for (int d = 32; d >= 8; d >>= 1) v += __shfl_down(v, d);
  float st[8];
#pragma unroll
  for (int j = 0; j < 8; ++j) st[j] = __shfl(v, j);

  const float inv = 1.0f / (float)B;
  float sc[4], sh[4];
#pragma unroll
  for (int j = 0; j < 4; ++j) {
    float mean = st[j] * inv;
    float var = st[4 + j] * inv - mean * mean;
    float is = rsqrtf(var + BN_EPS_F);
    sc[j] = gamma[j] * is;
    sh[j] = beta[j] - mean * sc[j];
  }
#pragma unroll
  for (int p = 0; p < 2; ++p) {
    int s = gtid + p * H;
    if (s < B) {
      float4 q = *(float4*)(out + (size_t)s * 4);
      *(float4*)(out + (size_t)s * 4) =
          make_float4(fmaf(q.x, sc[0], sh[0]), fmaf(q.y, sc[1], sh[1]),
                      fmaf(q.z, sc[2], sh[2]), fmaf(q.w, sc[3], sh[3]));
    }
  }
}

extern "C" void kernel_launch(void* const* d_in, const int* in_sizes, int n_in,
                              void* d_out, int out_size, void* d_ws, size_t ws_size,
                              hipStream_t stream) {
  const float* x = (const float*)d_in[0];
  const float* w = (const float*)d_in[1];
  const float* fc_w = (const float*)d_in[2];
  const float* gamma = (const float*)d_in[4];
  const float* beta = (const float*)d_in[5];
  float* out = (float*)d_out;
  float* wsf = (float*)d_ws;
  int B = in_sizes[0] / 16;

  k0_init<<<1, 128, 0, stream>>>(w, fc_w, wsf);

  // Host-side, capture-safe gate: barrier kernel requires full-grid
  // co-residency certified by the runtime.
  static int coop_state = -1;  // -1 unknown, 0 no, 1 yes
  if (coop_state < 0) {
    int dev = 0;
    (void)hipGetDevice(&dev);
    int ncu = 0;
    (void)hipDeviceGetAttribute(&ncu, hipDeviceAttributeMultiprocessorCount, dev);
    int per_cu = 0;
    (void)hipOccupancyMaxActiveBlocksPerMultiprocessor(&per_cu,
                                                       (const void*)fused2, NT, 0);
    coop_state =
        (ncu > 0 && per_cu > 0 && (long long)per_cu * ncu >= NBLK) ? 1 : 0;
  }

  if (coop_state == 1 && B <= 2 * NBLK * NT) {
    fused2<<<NBLK, NT, 0, stream>>>(x, wsf, out, B);
    k3s<<<NB2, NT, 0, stream>>>(out, wsf, gamma, beta, B);
  } else {
    k1_scan_tab<<<NB1, NT, 0, stream>>>(x, w, fc_w, wsf, B);
    k2_main<<<NB2, NT, 0, stream>>>(x, wsf, wsf + SSLOT_OFF, out, B);
    k3_final<<<NB2, NT, 0, stream>>>(out, wsf + SSLOT_OFF, gamma, beta, B);
  }
}

// Round 11
// 113.621 us; speedup vs baseline: 1.0397x; 1.0323x over previous
//
#include <hip/hip_runtime.h>
#include <math.h>

#define TWO_PI_F 6.28318530717958647692f
#define BN_EPS_F 1e-5f
#define NB1 2048  // k1 blocks (scan): 1 row/thread exactly at B=524288
#define NB2 1024  // k2/k3 blocks
#define NT 256

// ---------------------------------------------------------------------------
// Workspace layout (float offsets on d_ws). All cross-kernel data is written
// with plain stores in kernel N and read in kernel N+1 (runtime handles
// inter-kernel coherence). No atomics, no zero-init required.
//   [BMIN_OFF..+2048) : per-block min   (k1 -> k2)
//   [BMAX_OFF..+2048) : per-block max   (k1 -> k2)
//   [TAB_OFF..+576)   : UrT[16][16] | UiT[16][16] | AT[16][4]  (k1 -> k2)
//   [SSLOT_OFF..+8192): per-block BN stats [blk][8] = sum0..3,ssq0..3 (k2 -> k3)
// ---------------------------------------------------------------------------
#define BMIN_OFF 256
#define BMAX_OFF 2304
#define TAB_OFF 4352
#define SSLOT_OFF 4992

// ===========================================================================
// K1: min/max over x[:,0:4], 1 row/thread -> per-block slots; block 0 also
// builds the fixed circuit tables (U = weight-layer unitary, A = parity@fc_w).
// ===========================================================================
__global__ __launch_bounds__(NT) void k1_scan_tab(const float* __restrict__ x,
                                                  const float* __restrict__ w,
                                                  const float* __restrict__ fc_w,
                                                  float* __restrict__ wsf, int B) {
  int r = blockIdx.x * NT + threadIdx.x;
  float fmn = __builtin_inff(), fmx = -__builtin_inff();
  if (r < B) {
    float4 v = *(const float4*)(x + (size_t)r * 16);
    fmn = fminf(fminf(v.x, v.y), fminf(v.z, v.w));
    fmx = fmaxf(fmaxf(v.x, v.y), fmaxf(v.z, v.w));
  }
#pragma unroll
  for (int d = 32; d; d >>= 1) {
    fmn = fminf(fmn, __shfl_down(fmn, d));
    fmx = fmaxf(fmx, __shfl_down(fmx, d));
  }
  __shared__ float smn[4], smx[4];
  int wv = threadIdx.x >> 6, ln = threadIdx.x & 63;
  if (ln == 0) { smn[wv] = fmn; smx[wv] = fmx; }
  __syncthreads();
  if (threadIdx.x == 0) {
    wsf[BMIN_OFF + blockIdx.x] =
        fminf(fminf(smn[0], smn[1]), fminf(smn[2], smn[3]));
    wsf[BMAX_OFF + blockIdx.x] =
        fmaxf(fmaxf(smx[0], smx[1]), fmaxf(smx[2], smx[3]));
  }

  if (blockIdx.x == 0) {
    int tid = threadIdx.x;
    if (tid < 16) {
      // Column tid of the fixed 3-layer RY/RZ/CNOT unitary; store transposed.
      float sr[16], si[16];
#pragma unroll
      for (int k = 0; k < 16; ++k) { sr[k] = (k == tid) ? 1.f : 0.f; si[k] = 0.f; }
#pragma unroll
      for (int l = 0; l < 3; ++l) {
#pragma unroll
        for (int i = 0; i < 4; ++i) {
          const int m = 8 >> i;
          float ryc, rys, rzc, rzs;
          __sincosf(0.5f * w[(l * 4 + i) * 2 + 0], &rys, &ryc);
          __sincosf(0.5f * w[(l * 4 + i) * 2 + 1], &rzs, &rzc);
#pragma unroll
          for (int k = 0; k < 16; ++k) {
            if (!(k & m)) {
              int k1 = k | m;
              float a0r = sr[k], a0i = si[k], a1r = sr[k1], a1i = si[k1];
              sr[k] = ryc * a0r - rys * a1r;
              si[k] = ryc * a0i - rys * a1i;
              sr[k1] = rys * a0r + ryc * a1r;
              si[k1] = rys * a0i + ryc * a1i;
            }
          }
#pragma unroll
          for (int k = 0; k < 16; ++k) {
            float ps = (k & m) ? rzs : -rzs;
            float rr = sr[k], ii = si[k];
            sr[k] = rr * rzc - ii * ps;
            si[k] = rr * ps + ii * rzc;
          }
        }
#pragma unroll
        for (int c = 0; c < 4; ++c) {
          const int mc = 8 >> c;
          const int mt = 8 >> ((c + 1) & 3);
#pragma unroll
          for (int k = 0; k < 16; ++k) {
            if ((k & mc) && !(k & mt)) {
              int k2 = k | mt;
              float tt;
              tt = sr[k]; sr[k] = sr[k2]; sr[k2] = tt;
              tt = si[k]; si[k] = si[k2]; si[k2] = tt;
            }
          }
        }
      }
#pragma unroll
      for (int k = 0; k < 16; ++k) {
        wsf[TAB_OFF + tid * 16 + k] = sr[k];
        wsf[TAB_OFF + 256 + tid * 16 + k] = si[k];
      }
    } else if (tid == 16) {
      // AT[k][j] = sum_i fc_w[j][i] * Zparity(k,i)
      for (int k = 0; k < 16; ++k)
        for (int j = 0; j < 4; ++j) {
          float s = 0.f;
          for (int i = 0; i < 4; ++i)
            s += fc_w[j * 4 + i] * ((k & (8 >> i)) ? -1.f : 1.f);
          wsf[TAB_OFF + 512 + k * 4 + j] = s;
        }
    }
  }
}

// Two-sample fused circuit+linear: o = A|U v|^2 (no bias; constant bias
// cancels exactly in BatchNorm). tab -> wave-uniform scalar loads.
__device__ __forceinline__ void qfc_pair(const float* __restrict__ tab,
                                         const float* c0, const float* s0,
                                         const float* c1, const float* s1,
                                         float* o0, float* o1) {
  const float* __restrict__ Ur = tab;
  const float* __restrict__ Ui = tab + 256;
  const float* __restrict__ At = tab + 512;
  float A01_0[4] = {c0[0] * c0[1], c0[0] * s0[1], s0[0] * c0[1], s0[0] * s0[1]};
  float A23_0[4] = {c0[2] * c0[3], c0[2] * s0[3], s0[2] * c0[3], s0[2] * s0[3]};
  float A01_1[4] = {c1[0] * c1[1], c1[0] * s1[1], s1[0] * c1[1], s1[0] * s1[1]};
  float A23_1[4] = {c1[2] * c1[3], c1[2] * s1[3], s1[2] * c1[3], s1[2] * s1[3]};
  float yr0[16], yi0[16], yr1[16], yi1[16];
#pragma unroll
  for (int k = 0; k < 16; ++k) { yr0[k] = yi0[k] = yr1[k] = yi1[k] = 0.f; }
#pragma unroll
  for (int a = 0; a < 16; ++a) {
    float va0 = A01_0[a >> 2] * A23_0[a & 3];
    float va1 = A01_1[a >> 2] * A23_1[a & 3];
#pragma unroll
    for (int k = 0; k < 16; ++k) {
      float ur = Ur[a * 16 + k], ui = Ui[a * 16 + k];
      yr0[k] = fmaf(ur, va0, yr0[k]);
      yi0[k] = fmaf(ui, va0, yi0[k]);
      yr1[k] = fmaf(ur, va1, yr1[k]);
      yi1[k] = fmaf(ui, va1, yi1[k]);
    }
  }
#pragma unroll
  for (int j = 0; j < 4; ++j) { o0[j] = 0.f; o1[j] = 0.f; }
#pragma unroll
  for (int k = 0; k < 16; ++k) {
    float p0 = fmaf(yr0[k], yr0[k], yi0[k] * yi0[k]);
    float p1 = fmaf(yr1[k], yr1[k], yi1[k] * yi1[k]);
#pragma unroll
    for (int j = 0; j < 4; ++j) {
      float av = At[k * 4 + j];
      o0[j] = fmaf(av, p0, o0[j]);
      o1[j] = fmaf(av, p1, o1[j]);
    }
  }
}

// ===========================================================================
// K2: reduce min/max slots per-wave; 2 samples/thread circuit+linear; write
// pre-BN out; per-block BN stat partials -> plain-store slots [blk][8].
// ===========================================================================
__global__ __launch_bounds__(NT) void k2_main(const float* __restrict__ x,
                                              const float* __restrict__ wsf,
                                              float* __restrict__ sslot,
                                              float* __restrict__ out, int B) {
  const int tid = threadIdx.x;
  const int gtid = blockIdx.x * NT + tid;
  const int H = NB2 * NT;  // 262144
  const int wv = tid >> 6, ln = tid & 63;
  const float* __restrict__ tab = wsf + TAB_OFF;

  // global min/max from the 2048 k1 slots (redundant per-wave reduce)
  float gm = __builtin_inff(), gM = -__builtin_inff();
#pragma unroll
  for (int q = 0; q < NB1 / 64; ++q) {
    int i = ln + q * 64;
    gm = fminf(gm, wsf[BMIN_OFF + i]);
    gM = fmaxf(gM, wsf[BMAX_OFF + i]);
  }
#pragma unroll
  for (int d = 32; d; d >>= 1) {
    gm = fminf(gm, __shfl_down(gm, d));
    gM = fmaxf(gM, __shfl_down(gM, d));
  }
  gm = __shfl(gm, 0);
  gM = __shfl(gM, 0);
  const float ssc = TWO_PI_F * 0.5f / (gM - gm + 1e-8f);  // half-angle scale

  const int s0 = gtid, s1 = gtid + H;
  const bool h0 = s0 < B, h1 = s1 < B;
  float4 xa = h0 ? *(const float4*)(x + (size_t)s0 * 16) : make_float4(0, 0, 0, 0);
  float4 xb = h1 ? *(const float4*)(x + (size_t)s1 * 16) : make_float4(0, 0, 0, 0);

  float a0[4] = {xa.x, xa.y, xa.z, xa.w};
  float a1[4] = {xb.x, xb.y, xb.z, xb.w};
  float c0[4], sn0[4], c1[4], sn1[4];
#pragma unroll
  for (int i = 0; i < 4; ++i) {
    __sincosf((a0[i] - gm) * ssc, &sn0[i], &c0[i]);
    __sincosf((a1[i] - gm) * ssc, &sn1[i], &c1[i]);
  }
  float o0[4], o1[4];
  qfc_pair(tab, c0, sn0, c1, sn1, o0, o1);

  if (h0)
    *(float4*)(out + (size_t)s0 * 4) = make_float4(o0[0], o0[1], o0[2], o0[3]);
  if (h1)
    *(float4*)(out + (size_t)s1 * 4) = make_float4(o1[0], o1[1], o1[2], o1[3]);

  // per-block BN stat partials
  float vals[8];
#pragma unroll
  for (int j = 0; j < 4; ++j) {
    float v0 = h0 ? o0[j] : 0.f, v1 = h1 ? o1[j] : 0.f;
    vals[j] = v0 + v1;
    vals[4 + j] = fmaf(v0, v0, v1 * v1);
  }
#pragma unroll
  for (int j = 0; j < 8; ++j) {
#pragma unroll
    for (int d = 32; d; d >>= 1) vals[j] += __shfl_down(vals[j], d);
  }
  __shared__ float red[4][8];
  if (ln == 0) {
#pragma unroll
    for (int j = 0; j < 8; ++j) red[wv][j] = vals[j];
  }
  __syncthreads();
  if (tid < 8) {
    sslot[blockIdx.x * 8 + tid] =
        red[0][tid] + red[1][tid] + red[2][tid] + red[3][tid];
  }
}

// ===========================================================================
// K3: per-wave reduce of the 1024x8 stat slots (coalesced 64-float rows),
// then BN finalize in-place on out (2 float4s/thread).
// ===========================================================================
__global__ __launch_bounds__(NT) void k3_final(float* __restrict__ out,
                                               const float* __restrict__ sslot,
                                               const float* __restrict__ gamma,
                                               const float* __restrict__ beta,
                                               int B) {
  const int tid = threadIdx.x;
  const int gtid = blockIdx.x * NT + tid;
  const int H = NB2 * NT;
  const int ln = tid & 63;

  // flat element e = blk*8 + j; lane ln sums e ≡ ln (mod 64) -> j = ln&7
  float v = 0.f;
#pragma unroll
  for (int k = 0; k < (NB2 * 8) / 64; ++k) v += sslot[k * 64 + ln];
#pragma unroll
  for (int d = 32; d >= 8; d >>= 1) v += __shfl_down(v, d);
  // lanes 0..7 hold totals for j=0..7; broadcast all 8 to every lane
  float st[8];
#pragma unroll
  for (int j = 0; j < 8; ++j) st[j] = __shfl(v, j);

  const float inv = 1.0f / (float)B;
  float sc[4], sh[4];
#pragma unroll
  for (int j = 0; j < 4; ++j) {
    float mean = st[j] * inv;
    float var = st[4 + j] * inv - mean * mean;
    float is = rsqrtf(var + BN_EPS_F);
    sc[j] = gamma[j] * is;
    sh[j] = beta[j] - mean * sc[j];
  }
#pragma unroll
  for (int p = 0; p < 2; ++p) {
    int s = gtid + p * H;
    if (s < B) {
      float4 q = *(float4*)(out + (size_t)s * 4);
      *(float4*)(out + (size_t)s * 4) =
          make_float4(fmaf(q.x, sc[0], sh[0]), fmaf(q.y, sc[1], sh[1]),
                      fmaf(q.z, sc[2], sh[2]), fmaf(q.w, sc[3], sh[3]));
    }
  }
}

extern "C" void kernel_launch(void* const* d_in, const int* in_sizes, int n_in,
                              void* d_out, int out_size, void* d_ws, size_t ws_size,
                              hipStream_t stream) {
  const float* x = (const float*)d_in[0];
  const float* w = (const float*)d_in[1];
  const float* fc_w = (const float*)d_in[2];
  const float* gamma = (const float*)d_in[4];
  const float* beta = (const float*)d_in[5];
  float* out = (float*)d_out;
  float* wsf = (float*)d_ws;
  int B = in_sizes[0] / 16;

  k1_scan_tab<<<NB1, NT, 0, stream>>>(x, w, fc_w, wsf, B);
  k2_main<<<NB2, NT, 0, stream>>>(x, wsf, wsf + SSLOT_OFF, out, B);
  k3_final<<<NB2, NT, 0, stream>>>(out, wsf + SSLOT_OFF, gamma, beta, B);
}